// Round 11
// baseline (149.842 us; speedup 1.0000x reference)
//
#include <hip/hip_runtime.h>
#include <math.h>

// Problem constants
#define B_   32
#define L_   200

// ws layout (float offsets)
#define OFF_Q     0         // B*L*D = 409600
#define OFF_NQ    409600
#define OFF_Z     819200
#define OFF_V     1228800
#define OFF_SZ    1638400   // B*L
#define OFF_SV    1644800
#define OFF_SNQ   1651200
#define OFF_PZL   1657600   // B*D
#define OFF_PSL   1659648   // B*D*D
#define OFF_PNAM  1790720   // B*D*D
#define OFF_MPS2  1921792   // B
#define OFF_H     1921824   // B*L
#define OFF_C     1928224   // B*L
#define OFF_CP    1934624   // B*L*4
#define OFF_T1    1960224   // B*L*D
#define OFF_T2    2369824   // B*L*D
#define OFF_NAP   2779424   // B*4*4*64*64 = 2097152
#define OFF_SYR   4876576   // B*L
#define OFF_SY2R  4882976   // B*L
#define OFF_ZC    4889376   // B*L*D cumsum of z
// end 5298976 floats ~ 21.2 MB

__device__ __forceinline__ float wsum(float x){
#pragma unroll
  for (int o = 32; o > 0; o >>= 1) x += __shfl_xor(x, o, 64);
  return x;
}
__device__ __forceinline__ float eluf(float x){ return x > 0.f ? x : expm1f(x); }

// ================= K1: qzv (bid<200) + prompt (bid in [200,264)); W staged from original layout =================
__global__ __launch_bounds__(256) void k_qp(
    const float* __restrict__ x, const float* __restrict__ P, const float* __restrict__ Sp,
    const int* __restrict__ uid, const float* __restrict__ prev_z, const float* __restrict__ prev_s,
    const float* __restrict__ Wq, const float* __restrict__ Wk, const float* __restrict__ Wv,
    const float* __restrict__ bq, const float* __restrict__ bk, const float* __restrict__ bv,
    float* __restrict__ q, float* __restrict__ nq, float* __restrict__ z, float* __restrict__ v,
    float* __restrict__ sz, float* __restrict__ sv, float* __restrict__ snq,
    float* __restrict__ PzL, float* __restrict__ PsL, float* __restrict__ mps2,
    float* __restrict__ pNAM){
  __shared__ float smem[14752];
  int tid = threadIdx.x, bid = blockIdx.x;
  if (bid < 200){
    // ---- qzv: 32 rows/block; thread = (row r = tid>>3, d-group dg = tid&7) ----
    float* xs = smem;          // 32 rows x stride 257 = 8224 (odd stride: bank-spread scalar reads)
    float* wl = smem + 8224;   // 3 * 32*68 = 6528 (stride 68: float4-aligned, reads 2-way free)
    int row0 = bid * 32;
    for (int k = tid; k < 8192; k += 256){
      int rr = k >> 8, ii = k & 255;
      xs[rr*257 + ii] = x[row0*256 + k];
    }
    int r = tid >> 3, dg = tid & 7, d0 = dg * 8;
    float aq[8] = {0,0,0,0,0,0,0,0};
    float ak[8] = {0,0,0,0,0,0,0,0};
    float av[8] = {0,0,0,0,0,0,0,0};
    for (int c = 0; c < 8; c++){
      __syncthreads();
      for (int s = tid; s < 6144; s += 256){
        int il = s & 31, d_ = (s >> 5) & 63, m = s >> 11;
        const float* W = (m == 0) ? Wq : ((m == 1) ? Wk : Wv);
        wl[m*2176 + il*68 + d_] = W[d_*256 + c*32 + il];
      }
      __syncthreads();
      const float* xr = xs + r*257 + c*32;
      for (int il = 0; il < 32; il++){
        float xv = xr[il];
        const float* wr = wl + il*68 + d0;
        float4 a0 = *(const float4*)(wr);
        float4 a1 = *(const float4*)(wr + 4);
        float4 b0 = *(const float4*)(wr + 2176);
        float4 b1 = *(const float4*)(wr + 2180);
        float4 c0 = *(const float4*)(wr + 4352);
        float4 c1 = *(const float4*)(wr + 4356);
        aq[0]=fmaf(xv,a0.x,aq[0]); aq[1]=fmaf(xv,a0.y,aq[1]); aq[2]=fmaf(xv,a0.z,aq[2]); aq[3]=fmaf(xv,a0.w,aq[3]);
        aq[4]=fmaf(xv,a1.x,aq[4]); aq[5]=fmaf(xv,a1.y,aq[5]); aq[6]=fmaf(xv,a1.z,aq[6]); aq[7]=fmaf(xv,a1.w,aq[7]);
        ak[0]=fmaf(xv,b0.x,ak[0]); ak[1]=fmaf(xv,b0.y,ak[1]); ak[2]=fmaf(xv,b0.z,ak[2]); ak[3]=fmaf(xv,b0.w,ak[3]);
        ak[4]=fmaf(xv,b1.x,ak[4]); ak[5]=fmaf(xv,b1.y,ak[5]); ak[6]=fmaf(xv,b1.z,ak[6]); ak[7]=fmaf(xv,b1.w,ak[7]);
        av[0]=fmaf(xv,c0.x,av[0]); av[1]=fmaf(xv,c0.y,av[1]); av[2]=fmaf(xv,c0.z,av[2]); av[3]=fmaf(xv,c0.w,av[3]);
        av[4]=fmaf(xv,c1.x,av[4]); av[5]=fmaf(xv,c1.y,av[5]); av[6]=fmaf(xv,c1.z,av[6]); av[7]=fmaf(xv,c1.w,av[7]);
      }
    }
    float qv[8], zv[8], vv[8];
    float sq2 = 0.f, sq1 = 0.f, szp = 0.f, svp = 0.f;
#pragma unroll
    for (int j = 0; j < 8; j++){
      qv[j] = eluf(aq[j] + bq[d0+j]);
      zv[j] = eluf(ak[j] + bk[d0+j]);
      vv[j] = av[j] + bv[d0+j];
      sq2 += qv[j]*qv[j]; sq1 += qv[j]; szp += zv[j]; svp += vv[j];
    }
#pragma unroll
    for (int o = 1; o < 8; o <<= 1){
      sq2 += __shfl_xor(sq2, o, 64);
      sq1 += __shfl_xor(sq1, o, 64);
      szp += __shfl_xor(szp, o, 64);
      svp += __shfl_xor(svp, o, 64);
    }
    float inv = 1.f / (sqrtf(sq2) + 1e-8f);
    int row = row0 + r;
    *(float4*)(q + row*64 + d0)     = make_float4(qv[0],qv[1],qv[2],qv[3]);
    *(float4*)(q + row*64 + d0 + 4) = make_float4(qv[4],qv[5],qv[6],qv[7]);
    *(float4*)(nq + row*64 + d0)     = make_float4(qv[0]*inv,qv[1]*inv,qv[2]*inv,qv[3]*inv);
    *(float4*)(nq + row*64 + d0 + 4) = make_float4(qv[4]*inv,qv[5]*inv,qv[6]*inv,qv[7]*inv);
    *(float4*)(z + row*64 + d0)     = make_float4(zv[0],zv[1],zv[2],zv[3]);
    *(float4*)(z + row*64 + d0 + 4) = make_float4(zv[4],zv[5],zv[6],zv[7]);
    *(float4*)(v + row*64 + d0)     = make_float4(vv[0],vv[1],vv[2],vv[3]);
    *(float4*)(v + row*64 + d0 + 4) = make_float4(vv[4],vv[5],vv[6],vv[7]);
    if (dg == 0){ sz[row] = szp; sv[row] = svp; snq[row] = sq1*inv; }
    return;
  }
  // ---- prompt: g = bid-200; b = g&31; path = g>>5 (R8-proven: uniform xs reads, staged Wk/Wv) ----
  int g = bid - 200, b = g & 31, path = g >> 5;
  float* xs = smem;          // 2048
  float* wl = smem + 2048;   // 2*2176
  float* zs = smem + 6400;   // 512
  float* vs = smem + 6912;   // 512
  float* red = smem + 7424;  // 4
  float* facs = smem + 7428; // 1
  const float* src = path ? Sp : P;
  for (int k = tid; k < 2048; k += 256) xs[k] = src[b*2048 + k];
  int t0i = tid >> 6, d0i = tid & 63;
  float accK0 = 0.f, accV0 = 0.f, accK1 = 0.f, accV1 = 0.f;
  for (int c = 0; c < 8; c++){
    __syncthreads();
    for (int s = tid; s < 4096; s += 256){
      int il = s & 31, d_ = (s >> 5) & 63, m = s >> 11;
      const float* W = m ? Wv : Wk;
      wl[m*2176 + il*68 + d_] = W[d_*256 + c*32 + il];
    }
    __syncthreads();
    const float* x0 = xs + t0i*256 + c*32;
    const float* x1 = xs + (t0i+4)*256 + c*32;
    for (int il = 0; il < 32; il++){
      float wk_ = wl[il*68 + d0i];
      float wv_ = wl[2176 + il*68 + d0i];
      accK0 = fmaf(x0[il], wk_, accK0);
      accV0 = fmaf(x0[il], wv_, accV0);
      accK1 = fmaf(x1[il], wk_, accK1);
      accV1 = fmaf(x1[il], wv_, accV1);
    }
  }
  zs[tid]     = eluf(accK0 + bk[d0i]); vs[tid]     = accV0 + bv[d0i];
  zs[tid+256] = eluf(accK1 + bk[d0i]); vs[tid+256] = accV1 + bv[d0i];
  __syncthreads();
  float spv[16];
  float l1 = 0.f, l2 = 0.f;
  int p = tid >> 2, q0 = (tid & 3) * 16;
#pragma unroll
  for (int k = 0; k < 16; k++){
    int qq = q0 + k;
    float sp = 0.f;
#pragma unroll
    for (int t = 0; t < 8; t++) sp = fmaf(zs[t*64+p], vs[t*64+qq], sp);
    spv[k] = sp; l1 += sp; l2 += sp*sp;
  }
  float tot0, tot1;
  {
    float val = wsum(l1);
    if ((tid & 63) == 0) red[tid >> 6] = val;
    __syncthreads();
    tot0 = red[0] + red[1] + red[2] + red[3];
    __syncthreads();
    val = wsum(l2);
    if ((tid & 63) == 0) red[tid >> 6] = val;
    __syncthreads();
    tot1 = red[0] + red[1] + red[2] + red[3];
  }
  float mP = tot0 * (1.f/4096.f);
  float varP = tot1 * (1.f/4096.f) - mP*mP;
  float invv = rsqrtf(varP + 1e-5f);
  if (path == 0){
    if (tid == 0) mps2[b] = varP * invv * invv;  // E[PsL^2]
    if (tid < 64){
      int d = tid;
      float zc = 0.f;
#pragma unroll
      for (int t = 0; t < 8; t++) zc += zs[t*64+d];
      float s1 = wsum(zc), s2 = wsum(zc*zc);
      float mz = s1*(1.f/64.f), vz = s2*(1.f/64.f) - mz*mz;
      PzL[b*64+d] = (zc - mz) * rsqrtf(vz + 1e-5f);
    }
#pragma unroll
    for (int k = 0; k < 16; k++){
      int o = p*64 + q0 + k;
      PsL[b*4096 + o] = (spv[k] - mP) * invv;
    }
  } else {
    int u = uid[b];
    if (tid < 64){
      int d = tid;
      float zc = 0.f;
#pragma unroll
      for (int t = 0; t < 8; t++) zc += zs[t*64+d];
      float s1 = wsum(zc), s2 = wsum(zc*zc);
      float mz = s1*(1.f/64.f), vz = s2*(1.f/64.f) - mz*mz;
      float szl = (zc - mz) * rsqrtf(vz + 1e-5f);
      float pzv = prev_z[u*64 + d];
      float zu = pzv + szl;
      float zl2 = wsum(zu*zu);
      float psumv = wsum(pzv);
      float fac = ((psumv != 0.f) ? 1.f : 0.f) / (sqrtf(zl2) + 1e-8f);
      if (d == 0) facs[0] = fac;
    }
    __syncthreads();
    float fac = facs[0];
    const float* psrow = prev_s + (size_t)u * 4096;
#pragma unroll
    for (int k = 0; k < 16; k++){
      int o = p*64 + q0 + k;
      pNAM[b*4096 + o] = (psrow[o] + (spv[k] - mP) * invv) * fac;
    }
  }
}

// ================= K2: gram64 (pi<10) + t12 (pi in [10,17)) + Zcum (pi==17). Grid = 32*18 =================
#define PADK 68
__global__ __launch_bounds__(256) void k_stage2(
    const float* __restrict__ z, const float* __restrict__ v, const float* __restrict__ nq,
    const float* __restrict__ PsL, const float* __restrict__ pNAM,
    float* __restrict__ colpart, float* __restrict__ harr, float* __restrict__ carr,
    float* __restrict__ T1, float* __restrict__ T2, float* __restrict__ NAP,
    float* __restrict__ Zcum){
  __shared__ float smem[20480];   // 80 KiB exactly -> 2 blocks/CU
  int tid = threadIdx.x, bid = blockIdx.x;
  int b = bid / 18, pi = bid % 18;
  const float* zb = z + b*12800;
  const float* vb = v + b*12800;
  const float* nb = nq + b*12800;
  if (pi < 10){
    float* zlT = smem;
    float* vlT = smem + 4096;
    float* nlT = smem + 8192;    // reused as scsT after main phase
    float* ztT = smem + 12288;
    float* vtT = smem + 16384;
    int rt, ct;
    if (pi < 1){ rt = 0; ct = 0; }
    else if (pi < 3){ rt = 1; ct = pi - 1; }
    else if (pi < 6){ rt = 2; ct = pi - 3; }
    else { rt = 3; ct = pi - 6; }
    int l0 = rt*64, t0 = ct*64;
    {
      int r = tid & 63, kq = tid >> 6;
      int l = l0 + r, t = t0 + r;
      bool lv = l < L_, tv = t < L_;
#pragma unroll
      for (int m = 0; m < 4; m++){
        int k0 = kq*16 + m*4;
        float4 zr4 = lv ? *(const float4*)(zb + l*64 + k0) : make_float4(0,0,0,0);
        float4 vr4 = lv ? *(const float4*)(vb + l*64 + k0) : make_float4(0,0,0,0);
        float4 nr4 = lv ? *(const float4*)(nb + l*64 + k0) : make_float4(0,0,0,0);
        float4 zc4 = tv ? *(const float4*)(zb + t*64 + k0) : make_float4(0,0,0,0);
        float4 vc4 = tv ? *(const float4*)(vb + t*64 + k0) : make_float4(0,0,0,0);
        zlT[(k0+0)*64+r]=zr4.x; zlT[(k0+1)*64+r]=zr4.y; zlT[(k0+2)*64+r]=zr4.z; zlT[(k0+3)*64+r]=zr4.w;
        vlT[(k0+0)*64+r]=vr4.x; vlT[(k0+1)*64+r]=vr4.y; vlT[(k0+2)*64+r]=vr4.z; vlT[(k0+3)*64+r]=vr4.w;
        nlT[(k0+0)*64+r]=nr4.x; nlT[(k0+1)*64+r]=nr4.y; nlT[(k0+2)*64+r]=nr4.z; nlT[(k0+3)*64+r]=nr4.w;
        ztT[(k0+0)*64+r]=zc4.x; ztT[(k0+1)*64+r]=zc4.y; ztT[(k0+2)*64+r]=zc4.z; ztT[(k0+3)*64+r]=zc4.w;
        vtT[(k0+0)*64+r]=vc4.x; vtT[(k0+1)*64+r]=vc4.y; vtT[(k0+2)*64+r]=vc4.z; vtT[(k0+3)*64+r]=vc4.w;
      }
    }
    __syncthreads();
    int rg = tid >> 4, cg = tid & 15;
    int r0 = rg*4, c0 = cg*4;
    float az[16], av[16], an[16];
#pragma unroll
    for (int i = 0; i < 16; i++){ az[i]=0.f; av[i]=0.f; an[i]=0.f; }
    for (int k = 0; k < 64; k++){
      float4 zr4 = *(const float4*)&zlT[k*64 + r0];
      float4 vr4 = *(const float4*)&vlT[k*64 + r0];
      float4 nr4 = *(const float4*)&nlT[k*64 + r0];
      float4 zc4 = *(const float4*)&ztT[k*64 + c0];
      float4 vc4 = *(const float4*)&vtT[k*64 + c0];
      float zr[4] = {zr4.x, zr4.y, zr4.z, zr4.w};
      float vr[4] = {vr4.x, vr4.y, vr4.z, vr4.w};
      float nr[4] = {nr4.x, nr4.y, nr4.z, nr4.w};
      float zc[4] = {zc4.x, zc4.y, zc4.z, zc4.w};
      float vc[4] = {vc4.x, vc4.y, vc4.z, vc4.w};
#pragma unroll
      for (int i = 0; i < 4; i++){
#pragma unroll
        for (int j = 0; j < 4; j++){
          az[i*4+j] = fmaf(zr[i], zc[j], az[i*4+j]);
          av[i*4+j] = fmaf(vr[i], vc[j], av[i*4+j]);
          an[i*4+j] = fmaf(nr[i], zc[j], an[i*4+j]);
        }
      }
    }
    bool diag = (rt == ct);
    float prow[4];
#pragma unroll
    for (int i = 0; i < 4; i++){
      float s = 0.f;
#pragma unroll
      for (int j = 0; j < 4; j++){
        bool keep = !diag || (c0 + j <= r0 + i);
        if (keep) s += az[i*4+j] * av[i*4+j];
      }
      prow[i] = s;
    }
#pragma unroll
    for (int o = 1; o < 16; o <<= 1){
#pragma unroll
      for (int i = 0; i < 4; i++) prow[i] += __shfl_xor(prow[i], o, 64);
    }
    if (cg == 0){
#pragma unroll
      for (int i = 0; i < 4; i++){
        int l = l0 + r0 + i;
        if (l < L_) colpart[(b*L_ + l)*4 + ct] = prow[i];
      }
    }
    if (diag && rg == cg){
#pragma unroll
      for (int i = 0; i < 4; i++){
        int l = l0 + r0 + i;
        if (l < L_) harr[b*L_ + l] = az[i*4+i] * av[i*4+i];
      }
    }
    __syncthreads();
    float* scsT = nlT;
#pragma unroll
    for (int j = 0; j < 4; j++){
      int c = c0 + j;
      float m0 = (!diag || c <= r0+0) ? an[0*4+j] : 0.f;
      float m1 = (!diag || c <= r0+1) ? an[1*4+j] : 0.f;
      float m2 = (!diag || c <= r0+2) ? an[2*4+j] : 0.f;
      float m3 = (!diag || c <= r0+3) ? an[3*4+j] : 0.f;
      *(float4*)&scsT[c*64 + r0] = make_float4(m0, m1, m2, m3);
    }
    __syncthreads();
    {
      int d0 = c0;
      float o4[16];
#pragma unroll
      for (int i = 0; i < 16; i++) o4[i] = 0.f;
#pragma unroll 2
      for (int c = 0; c < 64; c++){
        float4 s4 = *(const float4*)&scsT[c*64 + r0];
        int t = t0 + c; if (t > L_-1) t = L_-1;   // masked scs==0 for t>=L_
        float4 v4 = *(const float4*)(vb + t*64 + d0);
        float sv4[4] = {s4.x, s4.y, s4.z, s4.w};
        float vv4[4] = {v4.x, v4.y, v4.z, v4.w};
#pragma unroll
        for (int i = 0; i < 4; i++){
#pragma unroll
          for (int j = 0; j < 4; j++) o4[i*4+j] = fmaf(sv4[i], vv4[j], o4[i*4+j]);
        }
      }
      float* nap = NAP + ((size_t)((b*4 + rt)*4 + ct))*4096;
#pragma unroll
      for (int i = 0; i < 4; i++)
        *(float4*)&nap[(r0+i)*64 + d0] = make_float4(o4[i*4+0], o4[i*4+1], o4[i*4+2], o4[i*4+3]);
    }
  } else if (pi < 17){
    float* zl  = smem;          // 32*68
    float* vl  = smem + 2176;
    float* nqt = smem + 4352;   // 32*65
    int rtile = pi - 10;
    int l0 = rtile * 32;
    for (int k = tid; k < 2048; k += 256){
      int r = k >> 6, d = k & 63, lr = l0 + r;
      bool ok = lr < L_;
      zl[r*PADK+d] = ok ? zb[lr*64 + d] : 0.f;
      vl[r*PADK+d] = ok ? vb[lr*64 + d] : 0.f;
      nqt[r*65+d]  = ok ? nb[lr*64 + d] : 0.f;
    }
    __syncthreads();
    {
      int w = tid >> 6, lane = tid & 63;
      float wacc[8] = {0,0,0,0,0,0,0,0};
      const float* psb = PsL + b*4096 + lane*64;
      for (int qq = 0; qq < 64; qq += 4){
        float4 p4 = *(const float4*)(psb + qq);
#pragma unroll
        for (int r8 = 0; r8 < 8; r8++){
          float4 v4 = *(const float4*)&vl[(w*8+r8)*PADK+qq];
          wacc[r8] += p4.x*v4.x + p4.y*v4.y + p4.z*v4.z + p4.w*v4.w;
        }
      }
#pragma unroll
      for (int r8 = 0; r8 < 8; r8++){
        int rr = w*8 + r8, l = l0 + rr;
        float c = wsum(zl[rr*PADK+lane] * wacc[r8]);
        if (lane == 0 && l < L_) carr[b*L_ + l] = c;
      }
    }
    {
      int r = tid & 31, c8 = tid >> 5, c0 = c8 * 8;
      float t1a[8] = {0,0,0,0,0,0,0,0}, t2a[8] = {0,0,0,0,0,0,0,0};
      const float* psm = PsL + b*4096;
      const float* pnm = pNAM + b*4096;
      for (int pp = 0; pp < 64; pp++){
        float nv = nqt[r*65 + pp];
        float4 a0 = *(const float4*)(psm + pp*64 + c0);
        float4 a1 = *(const float4*)(psm + pp*64 + c0 + 4);
        float4 b0 = *(const float4*)(pnm + pp*64 + c0);
        float4 b1 = *(const float4*)(pnm + pp*64 + c0 + 4);
        t1a[0]=fmaf(nv,a0.x,t1a[0]); t1a[1]=fmaf(nv,a0.y,t1a[1]); t1a[2]=fmaf(nv,a0.z,t1a[2]); t1a[3]=fmaf(nv,a0.w,t1a[3]);
        t1a[4]=fmaf(nv,a1.x,t1a[4]); t1a[5]=fmaf(nv,a1.y,t1a[5]); t1a[6]=fmaf(nv,a1.z,t1a[6]); t1a[7]=fmaf(nv,a1.w,t1a[7]);
        t2a[0]=fmaf(nv,b0.x,t2a[0]); t2a[1]=fmaf(nv,b0.y,t2a[1]); t2a[2]=fmaf(nv,b0.z,t2a[2]); t2a[3]=fmaf(nv,b0.w,t2a[3]);
        t2a[4]=fmaf(nv,b1.x,t2a[4]); t2a[5]=fmaf(nv,b1.y,t2a[5]); t2a[6]=fmaf(nv,b1.z,t2a[6]); t2a[7]=fmaf(nv,b1.w,t2a[7]);
      }
      int l = l0 + r;
      if (l < L_){
        float* t1p = T1 + (b*L_+l)*64 + c0;
        float* t2p = T2 + (b*L_+l)*64 + c0;
        *(float4*)(t1p)     = make_float4(t1a[0], t1a[1], t1a[2], t1a[3]);
        *(float4*)(t1p + 4) = make_float4(t1a[4], t1a[5], t1a[6], t1a[7]);
        *(float4*)(t2p)     = make_float4(t2a[0], t2a[1], t2a[2], t2a[3]);
        *(float4*)(t2p + 4) = make_float4(t2a[4], t2a[5], t2a[6], t2a[7]);
      }
    }
  } else {
    // ---- Zcum for batch b: 4 waves x 50-row chunks, 2-pass with chunk offsets ----
    int w = tid >> 6, d = tid & 63;
    float* ch = smem;  // 4*64
    float tot = 0.f;
    for (int i = 0; i < 50; i++) tot += zb[(w*50 + i)*64 + d];
    ch[w*64 + d] = tot;
    __syncthreads();
    float run = 0.f;
    for (int w2 = 0; w2 < w; w2++) run += ch[w2*64 + d];
    float* Zb = Zcum + b*12800;
    for (int i = 0; i < 50; i++){
      int l = w*50 + i;
      run += zb[l*64 + d];
      Zb[l*64 + d] = run;
    }
  }
}

// ================= K3: per (b,l) finred: Zcum read + prefix scalars + reduce + LN + std partials =================
__global__ __launch_bounds__(64) void k_finred(
    const float* __restrict__ Zcum, const float* __restrict__ q,
    const float* __restrict__ sz, const float* __restrict__ sv, const float* __restrict__ snq,
    const float* __restrict__ colpart, const float* __restrict__ harr, const float* __restrict__ carr,
    const float* __restrict__ PzL, const float* __restrict__ mps2,
    const float* __restrict__ T1, const float* __restrict__ T2, const float* __restrict__ NAP,
    float* __restrict__ out, float* __restrict__ Syr, float* __restrict__ Sy2r){
  int row = blockIdx.x;
  int b = row / 200, l = row % 200;
  int lane = threadIdx.x;
  float zcs = Zcum[row*64 + lane];
  float s1 = wsum(zcs), s2 = wsum(zcs*zcs);
  float mz = s1*(1.f/64.f), vz = s2*(1.f/64.f) - mz*mz;
  float zf = (zcs - mz) * rsqrtf(vz + 1e-5f) + PzL[b*64 + lane];
  float zl2 = wsum(zf*zf);
  float a = sqrtf(zl2) + 1e-8f;
  // prefix scalars over t<=l (thread-parallel + wsum)
  float pm = 0.f, pr = 0.f, pc = 0.f;
  for (int t = lane; t <= l; t += 64){
    int rt_ = b*200 + t;
    pm = fmaf(sz[rt_], sv[rt_], pm);
    int lt_ = t >> 6;
    float cs = 0.f;
#pragma unroll
    for (int j = 0; j < 4; j++) if (j <= lt_) cs += colpart[rt_*4 + j];
    pr += 2.f*cs - harr[rt_];
    pc += carr[rt_];
  }
  float cMv = wsum(pm);
  float cRv = wsum(pr);
  float cCs = wsum(pc);
  float m = cMv * (1.f/4096.f);
  float var = cRv * (1.f/4096.f) - m*m;
  float inv = rsqrtf(var + 1e-5f);
  float varT = inv*inv*var + 2.f*inv*cCs*(1.f/4096.f) + mps2[b];
  float invT = rsqrtf(varT + 1e-5f*a*a);
  float cAv = invT*inv;
  float cBv = invT*inv*m*snq[row];
  float cCv = invT;
  // std partials
  float y = q[row*64 + lane] / fmaxf(zf, 1e-6f);
  float ys = wsum(y), ys2 = wsum(y*y);
  if (lane == 0){ Syr[row] = ys; Sy2r[row] = ys2; }
  // NAP reduce
  int rt = l >> 6, rr = l & 63;
  const float* np_ = NAP + ((size_t)((b*4 + rt)*4))*4096 + rr*64 + lane;
  float acc = 0.f;
  for (int ct = 0; ct <= rt; ct++) acc += np_[ct*4096];
  float NA1 = cAv*acc - cBv + cCv*T1[row*64 + lane] + T2[row*64 + lane];
  float r1 = wsum(NA1), r2 = wsum(NA1*NA1);
  float mm = r1*(1.f/64.f), vv = r2*(1.f/64.f) - mm*mm;
  out[row*64 + lane] = (NA1 - mm) * rsqrtf(vv + 1e-5f);
}

// ================= K4: finalize std (ddof=1); reduce 6400 row partials =================
__global__ __launch_bounds__(256) void k_std(const float* __restrict__ Syr, const float* __restrict__ Sy2r,
    float* __restrict__ out){
  __shared__ float redA[4], redB[4];
  int tid = threadIdx.x, lane = tid & 63, g = tid >> 6;
  float a = 0.f, b2 = 0.f;
  for (int i = tid; i < 6400; i += 256){ a += Syr[i]; b2 += Sy2r[i]; }
  a = wsum(a); b2 = wsum(b2);
  if (lane == 0){ redA[g] = a; redB[g] = b2; }
  __syncthreads();
  if (tid == 0){
    float A = redA[0]+redA[1]+redA[2]+redA[3];
    float B2 = redB[0]+redB[1]+redB[2]+redB[3];
    const float N = 409600.f;
    float var = (B2 - A*A/N) / (N - 1.f);
    out[409600] = sqrtf(fmaxf(var, 0.f));
  }
}

extern "C" void kernel_launch(void* const* d_in, const int* in_sizes, int n_in,
                              void* d_out, int out_size, void* d_ws, size_t ws_size,
                              hipStream_t stream) {
  const int*   uid    = (const int*)d_in[0];
  const float* seqs   = (const float*)d_in[1];
  const float* P      = (const float*)d_in[2];
  const float* S      = (const float*)d_in[3];
  const float* prev_z = (const float*)d_in[4];
  const float* prev_s = (const float*)d_in[5];
  const float* Wq     = (const float*)d_in[6];
  const float* bq     = (const float*)d_in[7];
  const float* Wk     = (const float*)d_in[8];
  const float* bk     = (const float*)d_in[9];
  const float* Wv     = (const float*)d_in[10];
  const float* bv     = (const float*)d_in[11];
  float* w   = (float*)d_ws;
  float* out = (float*)d_out;

  k_qp<<<264, 256, 0, stream>>>(seqs, P, S, uid, prev_z, prev_s,
      Wq, Wk, Wv, bq, bk, bv,
      w + OFF_Q, w + OFF_NQ, w + OFF_Z, w + OFF_V,
      w + OFF_SZ, w + OFF_SV, w + OFF_SNQ,
      w + OFF_PZL, w + OFF_PSL, w + OFF_MPS2, w + OFF_PNAM);
  k_stage2<<<B_*18, 256, 0, stream>>>(w + OFF_Z, w + OFF_V, w + OFF_NQ,
      w + OFF_PSL, w + OFF_PNAM,
      w + OFF_CP, w + OFF_H, w + OFF_C,
      w + OFF_T1, w + OFF_T2, w + OFF_NAP,
      w + OFF_ZC);
  k_finred<<<6400, 64, 0, stream>>>(w + OFF_ZC, w + OFF_Q,
      w + OFF_SZ, w + OFF_SV, w + OFF_SNQ,
      w + OFF_CP, w + OFF_H, w + OFF_C,
      w + OFF_PZL, w + OFF_MPS2,
      w + OFF_T1, w + OFF_T2, w + OFF_NAP,
      out, w + OFF_SYR, w + OFF_SY2R);
  k_std<<<1, 256, 0, stream>>>(w + OFF_SYR, w + OFF_SY2R, out);
}

// Round 12
// 112.184 us; speedup vs baseline: 1.3357x; 1.3357x over previous
//
#include <hip/hip_runtime.h>
#include <math.h>

// Problem constants
#define B_   32
#define L_   200

// ws layout (float offsets)
#define OFF_WT    0         // 3*16384 transposed weights [i][d]
#define OFF_Q     49152     // B*L*D
#define OFF_NQ    458752
#define OFF_Z     868352
#define OFF_V     1277952
#define OFF_SZ    1687552   // B*L
#define OFF_SV    1693952
#define OFF_SNQ   1700352
#define OFF_PZL   1706752   // B*D
#define OFF_PSL   1708800   // B*D*D
#define OFF_PNAM  1839872   // B*D*D
#define OFF_MPS2  1970944   // B
#define OFF_H     1970976   // B*L
#define OFF_C     1977376   // B*L
#define OFF_CP    1983776   // B*L*4
#define OFF_T1    2009376   // B*L*D
#define OFF_T2    2418976   // B*L*D
#define OFF_NAP   2828576   // B*4*4*64*64 = 2097152
#define OFF_SYR   4925728   // B*L
#define OFF_SY2R  4932128   // B*L
#define OFF_ZC    4938528   // B*L*D cumsum of z
// end 5348128 floats ~ 21.4 MB

__device__ __forceinline__ float wsum(float x){
#pragma unroll
  for (int o = 32; o > 0; o >>= 1) x += __shfl_xor(x, o, 64);
  return x;
}
__device__ __forceinline__ float eluf(float x){ return x > 0.f ? x : expm1f(x); }

// K1: transpose Wq,Wk,Wv [64,256] -> [256,64]  (R10-proven)
__global__ __launch_bounds__(256) void k_transpose(const float* __restrict__ Wq,
    const float* __restrict__ Wk, const float* __restrict__ Wv, float* __restrict__ wt){
  int idx = blockIdx.x*256 + threadIdx.x;
  if (idx >= 3*16384) return;
  int m = idx >> 14, r = idx & 16383, i = r >> 6, d = r & 63;
  const float* W = (m==0) ? Wq : ((m==1) ? Wk : Wv);
  wt[m*16384 + i*64 + d] = W[d*256 + i];
}

// K2: merged qzv (bid<400) + prompt (bid in [400,464)); both read Wt from L2  (R10-proven)
__global__ __launch_bounds__(256) void k_qp(
    const float* __restrict__ x, const float* __restrict__ P, const float* __restrict__ Sp,
    const int* __restrict__ uid, const float* __restrict__ prev_z, const float* __restrict__ prev_s,
    const float* __restrict__ Wt,
    const float* __restrict__ bq, const float* __restrict__ bk, const float* __restrict__ bv,
    float* __restrict__ q, float* __restrict__ nq, float* __restrict__ z, float* __restrict__ v,
    float* __restrict__ sz, float* __restrict__ sv, float* __restrict__ snq,
    float* __restrict__ PzL, float* __restrict__ PsL, float* __restrict__ mps2,
    float* __restrict__ pNAM){
  __shared__ float smem[4096];
  int tid = threadIdx.x, bid = blockIdx.x;
  if (bid < 400){
    // ---- qzv: 16 rows/block, wave g owns rows g+4j (R6-proven) ----
    float* xs = smem;   // 16*256
    int row0 = bid * 16;
    int d = tid & 63, g = tid >> 6;
    for (int k = tid; k < 4096; k += 256) xs[k] = x[row0*256 + k];
    __syncthreads();
    const float* Wtq = Wt;
    const float* Wtk = Wt + 16384;
    const float* Wtv = Wt + 32768;
    float aq[4] = {0,0,0,0}, ak[4] = {0,0,0,0}, av[4] = {0,0,0,0};
    for (int i = 0; i < 256; i++){
      float wq = Wtq[i*64+d], wk = Wtk[i*64+d], wv = Wtv[i*64+d];
#pragma unroll
      for (int j = 0; j < 4; j++){
        float xv = xs[(g+4*j)*256 + i];
        aq[j] = fmaf(xv, wq, aq[j]);
        ak[j] = fmaf(xv, wk, ak[j]);
        av[j] = fmaf(xv, wv, av[j]);
      }
    }
    float bqd = bq[d], bkd = bk[d], bvd = bv[d];
#pragma unroll
    for (int j = 0; j < 4; j++){
      int r = row0 + g + 4*j;
      float qv = eluf(aq[j] + bqd);
      float zv = eluf(ak[j] + bkd);
      float vv = av[j] + bvd;
      float sq2 = wsum(qv*qv);
      float sq1 = wsum(qv);
      float szv = wsum(zv);
      float svv = wsum(vv);
      float inv = 1.f / (sqrtf(sq2) + 1e-8f);
      q[r*64+d] = qv; nq[r*64+d] = qv*inv; z[r*64+d] = zv; v[r*64+d] = vv;
      if (d == 0){ sz[r] = szv; sv[r] = svv; snq[r] = sq1*inv; }
    }
    return;
  }
  // ---- prompt: g2 = bid-400; b = g2&31; path = g2>>5 (R6-proven) ----
  int g2 = bid - 400, b = g2 & 31, path = g2 >> 5;
  float* xs = smem;            // 2048
  float* zs = smem + 2048;     // 512
  float* vs = smem + 2560;     // 512
  float* red = smem + 3072;    // 4
  float* facs = smem + 3076;   // 1
  const float* src = path ? Sp : P;
  for (int k = tid; k < 2048; k += 256) xs[k] = src[b*2048 + k];
  __syncthreads();
  const float* Wtk = Wt + 16384;
  const float* Wtv = Wt + 32768;
  for (int idx = tid; idx < 512; idx += 256){
    int t = idx >> 6, d = idx & 63;
    float ak = 0.f, av = 0.f;
    for (int i = 0; i < 256; i++){
      float xv = xs[t*256+i];
      ak = fmaf(xv, Wtk[i*64+d], ak);
      av = fmaf(xv, Wtv[i*64+d], av);
    }
    zs[idx] = eluf(ak + bk[d]); vs[idx] = av + bv[d];
  }
  __syncthreads();
  float spv[16];
  float l1 = 0.f, l2 = 0.f;
  int p = tid >> 2, q0 = (tid & 3) * 16;
#pragma unroll
  for (int k = 0; k < 16; k++){
    int qq = q0 + k;
    float sp = 0.f;
#pragma unroll
    for (int t = 0; t < 8; t++) sp = fmaf(zs[t*64+p], vs[t*64+qq], sp);
    spv[k] = sp; l1 += sp; l2 += sp*sp;
  }
  float tot0, tot1;
  {
    float val = wsum(l1);
    if ((tid & 63) == 0) red[tid >> 6] = val;
    __syncthreads();
    tot0 = red[0] + red[1] + red[2] + red[3];
    __syncthreads();
    val = wsum(l2);
    if ((tid & 63) == 0) red[tid >> 6] = val;
    __syncthreads();
    tot1 = red[0] + red[1] + red[2] + red[3];
  }
  float mP = tot0 * (1.f/4096.f);
  float varP = tot1 * (1.f/4096.f) - mP*mP;
  float invv = rsqrtf(varP + 1e-5f);
  if (path == 0){
    if (tid == 0) mps2[b] = varP * invv * invv;  // E[PsL^2]
    if (tid < 64){
      int d = tid;
      float zc = 0.f;
#pragma unroll
      for (int t = 0; t < 8; t++) zc += zs[t*64+d];
      float s1 = wsum(zc), s2 = wsum(zc*zc);
      float mz = s1*(1.f/64.f), vz = s2*(1.f/64.f) - mz*mz;
      PzL[b*64+d] = (zc - mz) * rsqrtf(vz + 1e-5f);
    }
#pragma unroll
    for (int k = 0; k < 16; k++){
      int o = p*64 + q0 + k;
      PsL[b*4096 + o] = (spv[k] - mP) * invv;
    }
  } else {
    int u = uid[b];
    if (tid < 64){
      int d = tid;
      float zc = 0.f;
#pragma unroll
      for (int t = 0; t < 8; t++) zc += zs[t*64+d];
      float s1 = wsum(zc), s2 = wsum(zc*zc);
      float mz = s1*(1.f/64.f), vz = s2*(1.f/64.f) - mz*mz;
      float szl = (zc - mz) * rsqrtf(vz + 1e-5f);
      float pzv = prev_z[u*64 + d];
      float zu = pzv + szl;
      float zl2 = wsum(zu*zu);
      float psumv = wsum(pzv);
      float fac = ((psumv != 0.f) ? 1.f : 0.f) / (sqrtf(zl2) + 1e-8f);
      if (d == 0) facs[0] = fac;
    }
    __syncthreads();
    float fac = facs[0];
    const float* psrow = prev_s + (size_t)u * 4096;
#pragma unroll
    for (int k = 0; k < 16; k++){
      int o = p*64 + q0 + k;
      pNAM[b*4096 + o] = (psrow[o] + (spv[k] - mP) * invv) * fac;
    }
  }
}

// K3: gram64 (pi<10) + t12 (pi in [10,17)) + Zcum (pi==17). Grid = 32*18
#define PADK 68
__global__ __launch_bounds__(256) void k_stage2(
    const float* __restrict__ z, const float* __restrict__ v, const float* __restrict__ nq,
    const float* __restrict__ PsL, const float* __restrict__ pNAM,
    float* __restrict__ colpart, float* __restrict__ harr, float* __restrict__ carr,
    float* __restrict__ T1, float* __restrict__ T2, float* __restrict__ NAP,
    float* __restrict__ Zcum){
  __shared__ float smem[20480];   // 80 KiB exactly -> 2 blocks/CU
  int tid = threadIdx.x, bid = blockIdx.x;
  int b = bid / 18, pi = bid % 18;
  const float* zb = z + b*12800;
  const float* vb = v + b*12800;
  const float* nb = nq + b*12800;
  if (pi < 10){
    float* zlT = smem;
    float* vlT = smem + 4096;
    float* nlT = smem + 8192;    // reused as scsT after main phase
    float* ztT = smem + 12288;
    float* vtT = smem + 16384;
    int rt, ct;
    if (pi < 1){ rt = 0; ct = 0; }
    else if (pi < 3){ rt = 1; ct = pi - 1; }
    else if (pi < 6){ rt = 2; ct = pi - 3; }
    else { rt = 3; ct = pi - 6; }
    int l0 = rt*64, t0 = ct*64;
    {
      int r = tid & 63, kq = tid >> 6;
      int l = l0 + r, t = t0 + r;
      bool lv = l < L_, tv = t < L_;
#pragma unroll
      for (int m = 0; m < 4; m++){
        int k0 = kq*16 + m*4;
        float4 zr4 = lv ? *(const float4*)(zb + l*64 + k0) : make_float4(0,0,0,0);
        float4 vr4 = lv ? *(const float4*)(vb + l*64 + k0) : make_float4(0,0,0,0);
        float4 nr4 = lv ? *(const float4*)(nb + l*64 + k0) : make_float4(0,0,0,0);
        float4 zc4 = tv ? *(const float4*)(zb + t*64 + k0) : make_float4(0,0,0,0);
        float4 vc4 = tv ? *(const float4*)(vb + t*64 + k0) : make_float4(0,0,0,0);
        zlT[(k0+0)*64+r]=zr4.x; zlT[(k0+1)*64+r]=zr4.y; zlT[(k0+2)*64+r]=zr4.z; zlT[(k0+3)*64+r]=zr4.w;
        vlT[(k0+0)*64+r]=vr4.x; vlT[(k0+1)*64+r]=vr4.y; vlT[(k0+2)*64+r]=vr4.z; vlT[(k0+3)*64+r]=vr4.w;
        nlT[(k0+0)*64+r]=nr4.x; nlT[(k0+1)*64+r]=nr4.y; nlT[(k0+2)*64+r]=nr4.z; nlT[(k0+3)*64+r]=nr4.w;
        ztT[(k0+0)*64+r]=zc4.x; ztT[(k0+1)*64+r]=zc4.y; ztT[(k0+2)*64+r]=zc4.z; ztT[(k0+3)*64+r]=zc4.w;
        vtT[(k0+0)*64+r]=vc4.x; vtT[(k0+1)*64+r]=vc4.y; vtT[(k0+2)*64+r]=vc4.z; vtT[(k0+3)*64+r]=vc4.w;
      }
    }
    __syncthreads();
    int rg = tid >> 4, cg = tid & 15;
    int r0 = rg*4, c0 = cg*4;
    float az[16], av[16], an[16];
#pragma unroll
    for (int i = 0; i < 16; i++){ az[i]=0.f; av[i]=0.f; an[i]=0.f; }
    for (int k = 0; k < 64; k++){
      float4 zr4 = *(const float4*)&zlT[k*64 + r0];
      float4 vr4 = *(const float4*)&vlT[k*64 + r0];
      float4 nr4 = *(const float4*)&nlT[k*64 + r0];
      float4 zc4 = *(const float4*)&ztT[k*64 + c0];
      float4 vc4 = *(const float4*)&vtT[k*64 + c0];
      float zr[4] = {zr4.x, zr4.y, zr4.z, zr4.w};
      float vr[4] = {vr4.x, vr4.y, vr4.z, vr4.w};
      float nr[4] = {nr4.x, nr4.y, nr4.z, nr4.w};
      float zc[4] = {zc4.x, zc4.y, zc4.z, zc4.w};
      float vc[4] = {vc4.x, vc4.y, vc4.z, vc4.w};
#pragma unroll
      for (int i = 0; i < 4; i++){
#pragma unroll
        for (int j = 0; j < 4; j++){
          az[i*4+j] = fmaf(zr[i], zc[j], az[i*4+j]);
          av[i*4+j] = fmaf(vr[i], vc[j], av[i*4+j]);
          an[i*4+j] = fmaf(nr[i], zc[j], an[i*4+j]);
        }
      }
    }
    bool diag = (rt == ct);
    float prow[4];
#pragma unroll
    for (int i = 0; i < 4; i++){
      float s = 0.f;
#pragma unroll
      for (int j = 0; j < 4; j++){
        bool keep = !diag || (c0 + j <= r0 + i);
        if (keep) s += az[i*4+j] * av[i*4+j];
      }
      prow[i] = s;
    }
#pragma unroll
    for (int o = 1; o < 16; o <<= 1){
#pragma unroll
      for (int i = 0; i < 4; i++) prow[i] += __shfl_xor(prow[i], o, 64);
    }
    if (cg == 0){
#pragma unroll
      for (int i = 0; i < 4; i++){
        int l = l0 + r0 + i;
        if (l < L_) colpart[(b*L_ + l)*4 + ct] = prow[i];
      }
    }
    if (diag && rg == cg){
#pragma unroll
      for (int i = 0; i < 4; i++){
        int l = l0 + r0 + i;
        if (l < L_) harr[b*L_ + l] = az[i*4+i] * av[i*4+i];
      }
    }
    __syncthreads();
    float* scsT = nlT;
#pragma unroll
    for (int j = 0; j < 4; j++){
      int c = c0 + j;
      float m0 = (!diag || c <= r0+0) ? an[0*4+j] : 0.f;
      float m1 = (!diag || c <= r0+1) ? an[1*4+j] : 0.f;
      float m2 = (!diag || c <= r0+2) ? an[2*4+j] : 0.f;
      float m3 = (!diag || c <= r0+3) ? an[3*4+j] : 0.f;
      *(float4*)&scsT[c*64 + r0] = make_float4(m0, m1, m2, m3);
    }
    __syncthreads();
    {
      int d0 = c0;
      float o4[16];
#pragma unroll
      for (int i = 0; i < 16; i++) o4[i] = 0.f;
#pragma unroll 2
      for (int c = 0; c < 64; c++){
        float4 s4 = *(const float4*)&scsT[c*64 + r0];
        int t = t0 + c; if (t > L_-1) t = L_-1;   // masked scs==0 for t>=L_
        float4 v4 = *(const float4*)(vb + t*64 + d0);
        float sv4[4] = {s4.x, s4.y, s4.z, s4.w};
        float vv4[4] = {v4.x, v4.y, v4.z, v4.w};
#pragma unroll
        for (int i = 0; i < 4; i++){
#pragma unroll
          for (int j = 0; j < 4; j++) o4[i*4+j] = fmaf(sv4[i], vv4[j], o4[i*4+j]);
        }
      }
      float* nap = NAP + ((size_t)((b*4 + rt)*4 + ct))*4096;
#pragma unroll
      for (int i = 0; i < 4; i++)
        *(float4*)&nap[(r0+i)*64 + d0] = make_float4(o4[i*4+0], o4[i*4+1], o4[i*4+2], o4[i*4+3]);
    }
  } else if (pi < 17){
    float* zl  = smem;          // 32*68
    float* vl  = smem + 2176;
    float* nqt = smem + 4352;   // 32*65
    int rtile = pi - 10;
    int l0 = rtile * 32;
    for (int k = tid; k < 2048; k += 256){
      int r = k >> 6, d = k & 63, lr = l0 + r;
      bool ok = lr < L_;
      zl[r*PADK+d] = ok ? zb[lr*64 + d] : 0.f;
      vl[r*PADK+d] = ok ? vb[lr*64 + d] : 0.f;
      nqt[r*65+d]  = ok ? nb[lr*64 + d] : 0.f;
    }
    __syncthreads();
    {
      int w = tid >> 6, lane = tid & 63;
      float wacc[8] = {0,0,0,0,0,0,0,0};
      const float* psb = PsL + b*4096 + lane*64;
      for (int qq = 0; qq < 64; qq += 4){
        float4 p4 = *(const float4*)(psb + qq);
#pragma unroll
        for (int r8 = 0; r8 < 8; r8++){
          float4 v4 = *(const float4*)&vl[(w*8+r8)*PADK+qq];
          wacc[r8] += p4.x*v4.x + p4.y*v4.y + p4.z*v4.z + p4.w*v4.w;
        }
      }
#pragma unroll
      for (int r8 = 0; r8 < 8; r8++){
        int rr = w*8 + r8, l = l0 + rr;
        float c = wsum(zl[rr*PADK+lane] * wacc[r8]);
        if (lane == 0 && l < L_) carr[b*L_ + l] = c;
      }
    }
    {
      int r = tid & 31, c8 = tid >> 5, c0 = c8 * 8;
      float t1a[8] = {0,0,0,0,0,0,0,0}, t2a[8] = {0,0,0,0,0,0,0,0};
      const float* psm = PsL + b*4096;
      const float* pnm = pNAM + b*4096;
      for (int pp = 0; pp < 64; pp++){
        float nv = nqt[r*65 + pp];
        float4 a0 = *(const float4*)(psm + pp*64 + c0);
        float4 a1 = *(const float4*)(psm + pp*64 + c0 + 4);
        float4 b0 = *(const float4*)(pnm + pp*64 + c0);
        float4 b1 = *(const float4*)(pnm + pp*64 + c0 + 4);
        t1a[0]=fmaf(nv,a0.x,t1a[0]); t1a[1]=fmaf(nv,a0.y,t1a[1]); t1a[2]=fmaf(nv,a0.z,t1a[2]); t1a[3]=fmaf(nv,a0.w,t1a[3]);
        t1a[4]=fmaf(nv,a1.x,t1a[4]); t1a[5]=fmaf(nv,a1.y,t1a[5]); t1a[6]=fmaf(nv,a1.z,t1a[6]); t1a[7]=fmaf(nv,a1.w,t1a[7]);
        t2a[0]=fmaf(nv,b0.x,t2a[0]); t2a[1]=fmaf(nv,b0.y,t2a[1]); t2a[2]=fmaf(nv,b0.z,t2a[2]); t2a[3]=fmaf(nv,b0.w,t2a[3]);
        t2a[4]=fmaf(nv,b1.x,t2a[4]); t2a[5]=fmaf(nv,b1.y,t2a[5]); t2a[6]=fmaf(nv,b1.z,t2a[6]); t2a[7]=fmaf(nv,b1.w,t2a[7]);
      }
      int l = l0 + r;
      if (l < L_){
        float* t1p = T1 + (b*L_+l)*64 + c0;
        float* t2p = T2 + (b*L_+l)*64 + c0;
        *(float4*)(t1p)     = make_float4(t1a[0], t1a[1], t1a[2], t1a[3]);
        *(float4*)(t1p + 4) = make_float4(t1a[4], t1a[5], t1a[6], t1a[7]);
        *(float4*)(t2p)     = make_float4(t2a[0], t2a[1], t2a[2], t2a[3]);
        *(float4*)(t2p + 4) = make_float4(t2a[4], t2a[5], t2a[6], t2a[7]);
      }
    }
  } else {
    // ---- Zcum for batch b: 4 waves x 50-row chunks, 2-pass with chunk offsets ----
    int w = tid >> 6, d = tid & 63;
    float* ch = smem;  // 4*64
    float tot = 0.f;
    for (int i = 0; i < 50; i++) tot += zb[(w*50 + i)*64 + d];
    ch[w*64 + d] = tot;
    __syncthreads();
    float run = 0.f;
    for (int w2 = 0; w2 < w; w2++) run += ch[w2*64 + d];
    float* Zb = Zcum + b*12800;
    for (int i = 0; i < 50; i++){
      int l = w*50 + i;
      run += zb[l*64 + d];
      Zb[l*64 + d] = run;
    }
  }
}

// K4: per (b,l) finred: Zcum read + prefix scalars + reduce + LN + std partials
__global__ __launch_bounds__(64) void k_finred(
    const float* __restrict__ Zcum, const float* __restrict__ q,
    const float* __restrict__ sz, const float* __restrict__ sv, const float* __restrict__ snq,
    const float* __restrict__ colpart, const float* __restrict__ harr, const float* __restrict__ carr,
    const float* __restrict__ PzL, const float* __restrict__ mps2,
    const float* __restrict__ T1, const float* __restrict__ T2, const float* __restrict__ NAP,
    float* __restrict__ out, float* __restrict__ Syr, float* __restrict__ Sy2r){
  int row = blockIdx.x;
  int b = row / 200, l = row % 200;
  int lane = threadIdx.x;
  float zcs = Zcum[row*64 + lane];
  float s1 = wsum(zcs), s2 = wsum(zcs*zcs);
  float mz = s1*(1.f/64.f), vz = s2*(1.f/64.f) - mz*mz;
  float zf = (zcs - mz) * rsqrtf(vz + 1e-5f) + PzL[b*64 + lane];
  float zl2 = wsum(zf*zf);
  float a = sqrtf(zl2) + 1e-8f;
  // prefix scalars over t<=l (thread-parallel + wsum)
  float pm = 0.f, pr = 0.f, pc = 0.f;
  for (int t = lane; t <= l; t += 64){
    int rt_ = b*200 + t;
    pm = fmaf(sz[rt_], sv[rt_], pm);
    int lt_ = t >> 6;
    float cs = 0.f;
#pragma unroll
    for (int j = 0; j < 4; j++) if (j <= lt_) cs += colpart[rt_*4 + j];
    pr += 2.f*cs - harr[rt_];
    pc += carr[rt_];
  }
  float cMv = wsum(pm);
  float cRv = wsum(pr);
  float cCs = wsum(pc);
  float m = cMv * (1.f/4096.f);
  float var = cRv * (1.f/4096.f) - m*m;
  float inv = rsqrtf(var + 1e-5f);
  float varT = inv*inv*var + 2.f*inv*cCs*(1.f/4096.f) + mps2[b];
  float invT = rsqrtf(varT + 1e-5f*a*a);
  float cAv = invT*inv;
  float cBv = invT*inv*m*snq[row];
  float cCv = invT;
  // std partials
  float y = q[row*64 + lane] / fmaxf(zf, 1e-6f);
  float ys = wsum(y), ys2 = wsum(y*y);
  if (lane == 0){ Syr[row] = ys; Sy2r[row] = ys2; }
  // NAP reduce
  int rt = l >> 6, rr = l & 63;
  const float* np_ = NAP + ((size_t)((b*4 + rt)*4))*4096 + rr*64 + lane;
  float acc = 0.f;
  for (int ct = 0; ct <= rt; ct++) acc += np_[ct*4096];
  float NA1 = cAv*acc - cBv + cCv*T1[row*64 + lane] + T2[row*64 + lane];
  float r1 = wsum(NA1), r2 = wsum(NA1*NA1);
  float mm = r1*(1.f/64.f), vv = r2*(1.f/64.f) - mm*mm;
  out[row*64 + lane] = (NA1 - mm) * rsqrtf(vv + 1e-5f);
}

// K5: finalize std (ddof=1); reduce 6400 row partials
__global__ __launch_bounds__(256) void k_std(const float* __restrict__ Syr, const float* __restrict__ Sy2r,
    float* __restrict__ out){
  __shared__ float redA[4], redB[4];
  int tid = threadIdx.x, lane = tid & 63, g = tid >> 6;
  float a = 0.f, b2 = 0.f;
  for (int i = tid; i < 6400; i += 256){ a += Syr[i]; b2 += Sy2r[i]; }
  a = wsum(a); b2 = wsum(b2);
  if (lane == 0){ redA[g] = a; redB[g] = b2; }
  __syncthreads();
  if (tid == 0){
    float A = redA[0]+redA[1]+redA[2]+redA[3];
    float B2 = redB[0]+redB[1]+redB[2]+redB[3];
    const float N = 409600.f;
    float var = (B2 - A*A/N) / (N - 1.f);
    out[409600] = sqrtf(fmaxf(var, 0.f));
  }
}

extern "C" void kernel_launch(void* const* d_in, const int* in_sizes, int n_in,
                              void* d_out, int out_size, void* d_ws, size_t ws_size,
                              hipStream_t stream) {
  const int*   uid    = (const int*)d_in[0];
  const float* seqs   = (const float*)d_in[1];
  const float* P      = (const float*)d_in[2];
  const float* S      = (const float*)d_in[3];
  const float* prev_z = (const float*)d_in[4];
  const float* prev_s = (const float*)d_in[5];
  const float* Wq     = (const float*)d_in[6];
  const float* bq     = (const float*)d_in[7];
  const float* Wk     = (const float*)d_in[8];
  const float* bk     = (const float*)d_in[9];
  const float* Wv     = (const float*)d_in[10];
  const float* bv     = (const float*)d_in[11];
  float* w   = (float*)d_ws;
  float* out = (float*)d_out;

  k_transpose<<<192, 256, 0, stream>>>(Wq, Wk, Wv, w + OFF_WT);
  k_qp<<<464, 256, 0, stream>>>(seqs, P, S, uid, prev_z, prev_s,
      w + OFF_WT, bq, bk, bv,
      w + OFF_Q, w + OFF_NQ, w + OFF_Z, w + OFF_V,
      w + OFF_SZ, w + OFF_SV, w + OFF_SNQ,
      w + OFF_PZL, w + OFF_PSL, w + OFF_MPS2, w + OFF_PNAM);
  k_stage2<<<B_*18, 256, 0, stream>>>(w + OFF_Z, w + OFF_V, w + OFF_NQ,
      w + OFF_PSL, w + OFF_PNAM,
      w + OFF_CP, w + OFF_H, w + OFF_C,
      w + OFF_T1, w + OFF_T2, w + OFF_NAP,
      w + OFF_ZC);
  k_finred<<<6400, 64, 0, stream>>>(w + OFF_ZC, w + OFF_Q,
      w + OFF_SZ, w + OFF_SV, w + OFF_SNQ,
      w + OFF_CP, w + OFF_H, w + OFF_C,
      w + OFF_PZL, w + OFF_MPS2,
      w + OFF_T1, w + OFF_T2, w + OFF_NAP,
      out, w + OFF_SYR, w + OFF_SY2R);
  k_std<<<1, 256, 0, stream>>>(w + OFF_SYR, w + OFF_SY2R, out);
}